// Round 6
// baseline (61.881 us; speedup 1.0000x reference)
//
#include <hip/hip_runtime.h>

#define BB 32
#define CC 16
#define HH 256
#define WW 256
#define HWSZ (HH * WW)

#define TW 64                  // tile width (x)
#define TH 16                  // tile height (y)
#define NBLK (BB * (WW/TW) * (HH/TH))   // 2048 blocks
#define NXCD 8

#define SROWS 48               // staged row capacity
#define SCOLS 104              // row stride: phase 8/row tiles 32 banks for stride-1 lanes
#define MAXF4 26               // 104/4
#define KMAX 5                 // ceil(48*26/256)

typedef float f2 __attribute__((ext_vector_type(2)));
typedef float f4 __attribute__((ext_vector_type(4)));

__global__ __launch_bounds__(256) void st_lds3_kernel(
    const float* __restrict__ input,   // [B,C,H,W]
    const float* __restrict__ theta,   // [B,6]
    float* __restrict__ out)           // [B,C,H,W]
{
    __shared__ float S[SROWS * SCOLS];   // 19.97 KB -> 8 blocks/CU

    // Chunked XCD swizzle (2048 % 8 == 0, bijective)
    int bid = blockIdx.x;
    int wg = (bid & (NXCD - 1)) * (NBLK / NXCD) + (bid >> 3);

    int b  = wg >> 6;              // 64 tiles per image
    int r  = wg & 63;
    int yt = r >> 2;               // 16 y-tiles
    int xt = r & 3;                // 4 x-tiles

    int tid = threadIdx.x;
    int qy = tid >> 4;             // 0..15 row in tile
    int qx = tid & 15;             // 0..15 base col; pixels at qx + 16*j
    int oy  = yt * TH + qy;
    int oxb = xt * TW + qx;        // pixel j at oxb + 16*j

    const float* th = theta + b * 6;
    float t0 = th[0], t1 = th[1], t2 = th[2];
    float t3 = th[3], t4 = th[4], t5 = th[5];

    const float step = 2.0f / 255.0f;

    // ---- staging window from tile-corner bounds (affine + monotone clip) ----
    float gxa = -1.0f + (xt * TW) * step;
    float gxb = -1.0f + (xt * TW + TW - 1) * step;
    float gya = -1.0f + (yt * TH) * step;
    float gyb = -1.0f + (yt * TH + TH - 1) * step;

    float x00 = t0 * gxa + t1 * gya + t2, x01 = t0 * gxa + t1 * gyb + t2;
    float x10 = t0 * gxb + t1 * gya + t2, x11 = t0 * gxb + t1 * gyb + t2;
    float y00 = t3 * gxa + t4 * gya + t5, y01 = t3 * gxa + t4 * gyb + t5;
    float y10 = t3 * gxb + t4 * gya + t5, y11 = t3 * gxb + t4 * gyb + t5;

    float xmn = fminf(fminf(x00, x01), fminf(x10, x11));
    float xmx = fmaxf(fmaxf(x00, x01), fmaxf(x10, x11));
    float ymn = fminf(fminf(y00, y01), fminf(y10, y11));
    float ymx = fmaxf(fmaxf(y00, y01), fmaxf(y10, y11));
    xmn = fminf(fmaxf(xmn, -1.0f), 1.0f);
    xmx = fminf(fmaxf(xmx, -1.0f), 1.0f);
    ymn = fminf(fmaxf(ymn, -1.0f), 1.0f);
    ymx = fminf(fmaxf(ymx, -1.0f), 1.0f);
    float pxmn = (xmn + 1.0f) * 127.5f, pxmx = (xmx + 1.0f) * 127.5f;
    float pymn = (ymn + 1.0f) * 127.5f, pymx = (ymx + 1.0f) * 127.5f;

    int cx0 = (int)floorf(pxmn) - 1;
    cx0 = (max(0, min(cx0, WW - 4))) & ~3;              // 16B-aligned start
    int cxend = min((int)floorf(pxmx) + 2, WW - 1);     // inclusive
    int wf4 = (cxend - cx0 + 4) >> 2;
    wf4 = min(wf4, min(MAXF4, (WW - cx0) >> 2));
    int wcols = wf4 * 4;

    int ry0 = (int)floorf(pymn) - 1;
    ry0 = max(0, min(ry0, HH - 1));
    int ryend = min((int)floorf(pymx) + 2, HH - 1);
    int rows = min(min(ryend - ry0 + 1, SROWS), HH - ry0);
    int nf4 = rows * wf4;

    // ---- precompute stage slots ONCE (channel-invariant) ----
    int  sg[KMAX], sl[KMAX];
    bool sv[KMAX];
    #pragma unroll
    for (int k = 0; k < KMAX; ++k) {
        int idx = tid + k * 256;
        sv[k] = idx < nf4;
        int rr = idx / wf4;
        int cq = idx - rr * wf4;
        sg[k] = rr * WW + cq * 4;      // global float offset within window
        sl[k] = rr * SCOLS + cq * 4;   // LDS float offset (16B-aligned)
    }

    // ---- per-pixel offsets & weights (channel-invariant) ----
    int   off[4], goff[4];
    float w00[4], w01[4], w10[4], w11[4];
    bool  ok[4];
    float gy = -1.0f + oy * step;
    float cxp = t1 * gy + t2;
    float cyp = t4 * gy + t5;

    #pragma unroll
    for (int j = 0; j < 4; ++j) {
        float gx = -1.0f + (oxb + 16 * j) * step;
        float xs = fminf(fmaxf(t0 * gx + cxp, -1.0f), 1.0f);
        float ys = fminf(fmaxf(t3 * gx + cyp, -1.0f), 1.0f);
        float x = (xs + 1.0f) * 127.5f;
        float y = (ys + 1.0f) * 127.5f;
        // bx=min(floor(x),254), fx=x-bx in [0,1]: exact index-clamp semantics
        float bxf = fminf(floorf(x), 254.0f);
        float byf = fminf(floorf(y), 254.0f);
        float fx = x - bxf, fy = y - byf;
        int bx = (int)bxf, by = (int)byf;

        w00[j] = (1.0f - fx) * (1.0f - fy);
        w01[j] = fx * (1.0f - fy);
        w10[j] = (1.0f - fx) * fy;
        w11[j] = fx * fy;

        int lx = bx - cx0, ly = by - ry0;
        ok[j] = (lx >= 0) && (lx <= wcols - 2) && (ly >= 0) && (ly <= rows - 2);
        off[j]  = ly * SCOLS + lx;
        goff[j] = by * WW + bx;
    }

    const float* ibase = input + (size_t)b * CC * HWSZ;
    float* obase = out + (size_t)b * CC * HWSZ + (size_t)oy * WW + oxb;

    for (int c = 0; c < CC; ++c) {
        __syncthreads();               // previous iteration done reading S
        const float* src = ibase + c * HWSZ + ry0 * WW + cx0;
        #pragma unroll
        for (int k = 0; k < KMAX; ++k) {
            if (sv[k]) {
                *(f4*)&S[sl[k]] = *(const f4*)(src + sg[k]);   // ds_write_b128, aligned
            }
        }
        __syncthreads();

        const float* p = ibase + c * HWSZ;
        float* q = obase + c * HWSZ;
        #pragma unroll
        for (int j = 0; j < 4; ++j) {
            float v00, v01, v10, v11;
            if (ok[j]) {
                v00 = S[off[j]];               // ds_read2_b32 {0,1}
                v01 = S[off[j] + 1];
                v10 = S[off[j] + SCOLS];       // ds_read2_b32 {104,105}
                v11 = S[off[j] + SCOLS + 1];
            } else {
                f2 a, bb;   // exact global fallback (rare)
                __builtin_memcpy(&a,  p + goff[j], 8);
                __builtin_memcpy(&bb, p + goff[j] + WW, 8);
                v00 = a.x; v01 = a.y; v10 = bb.x; v11 = bb.y;
            }
            q[16 * j] = v00 * w00[j] + v01 * w01[j] + v10 * w10[j] + v11 * w11[j];
        }
    }
}

extern "C" void kernel_launch(void* const* d_in, const int* in_sizes, int n_in,
                              void* d_out, int out_size, void* d_ws, size_t ws_size,
                              hipStream_t stream) {
    const float* input = (const float*)d_in[0];
    const float* theta = (const float*)d_in[1];
    float* out = (float*)d_out;

    dim3 block(256);
    dim3 grid(NBLK);   // 2048 blocks
    hipLaunchKernelGGL(st_lds3_kernel, grid, block, 0, stream,
                       input, theta, out);
}